// Round 3
// baseline (324.944 us; speedup 1.0000x reference)
//
#include <hip/hip_runtime.h>

#define B_ 8
#define C_ 32
#define NI 256   // coarse positions (16x16)
#define C4 8192  // merged channels = 32*256

typedef _Float16 f16;
typedef __attribute__((ext_vector_type(8))) _Float16 f16x8;
typedef __attribute__((ext_vector_type(4))) _Float16 f16x4;
typedef __attribute__((ext_vector_type(2))) _Float16 f16x2;
typedef __attribute__((ext_vector_type(4))) float f32x4;

__device__ __forceinline__ int dh_of(int t) { return (t & 1) | ((t >> 1) & 2) | ((t >> 2) & 4) | ((t >> 3) & 8); }
__device__ __forceinline__ int dw_of(int t) { return ((t >> 1) & 1) | ((t >> 2) & 2) | ((t >> 3) & 4) | ((t >> 4) & 8); }

// ---------------------------------------------------------------------------
// K1: depthwise 3x3 conv (Q,K) + identity (V), permuted to [b][i][c4] f16.
// x staged in LDS as f16 (22.5KB -> 6 blocks/CU). Interior via aligned float4.
// LDS layout: xs[c][r][cc], r in 0..17 (gh = hi*16-1+r), cc = gw - wi*16 + 2
// (cc in 1..18), row stride 20 f16. Weights as f16 [c][16] for f16x8 reads.
// ---------------------------------------------------------------------------
__global__ __launch_bounds__(256) void k1_conv_permute(
    const float* __restrict__ x, const float* __restrict__ wq, const float* __restrict__ bq,
    const float* __restrict__ wk, const float* __restrict__ bk,
    f16* __restrict__ Qt, f16* __restrict__ Kt, f16* __restrict__ Vt)
{
  __shared__ __align__(16) f16 xs[C_ * 360];   // 23040 B
  __shared__ __align__(16) f16 wqh[C_ * 16];   // 1 KB
  __shared__ __align__(16) f16 wkh[C_ * 16];   // 1 KB
  __shared__ float bqs[C_], bks[C_];
  const int bid = blockIdx.x;
  const int b = bid >> 8, i = bid & 255;
  const int hi = i >> 4, wi = i & 15;
  const int tid = threadIdx.x;

  // BUG FIX (round 2 -> 3): must loop, 288 > 256 threads
  for (int idx = tid; idx < 288; idx += 256) {
    const int c = idx / 9, t9 = idx - c * 9;
    wqh[c * 16 + t9] = (f16)wq[idx];
    wkh[c * 16 + t9] = (f16)wk[idx];
  }
  if (tid >= 224 && tid < 256) { bqs[tid - 224] = bq[tid - 224]; bks[tid - 224] = bk[tid - 224]; }

  const size_t xb = ((size_t)b * C_) << 16;
  // interior: 32c x 16r x 4 float4 = 2048 -> 8 per thread, aligned & coalesced
#pragma unroll
  for (int e = 0; e < 8; ++e) {
    const int u = tid + 256 * e;
    const int c = u >> 6, rem = u & 63;
    const int r16 = rem >> 2, k4 = rem & 3;
    const int gh = hi * 16 + r16, gw = wi * 16 + k4 * 4;
    const f32x4 xv = *(const f32x4*)(x + xb + ((size_t)c << 16) + gh * 256 + gw);
    const int base = c * 360 + (r16 + 1) * 20 + (2 + 4 * k4);
    f16x2 p0; p0[0] = (f16)xv[0]; p0[1] = (f16)xv[1];
    f16x2 p1; p1[0] = (f16)xv[2]; p1[1] = (f16)xv[3];
    *(f16x2*)&xs[base] = p0;
    *(f16x2*)&xs[base + 2] = p1;
  }
  // halo: 68 per channel x 32 = 2176 scalar
  const int h0 = hi * 16 - 1;
#pragma unroll
  for (int e = 0; e < 9; ++e) {
    const int u = tid + 256 * e;
    if (u < 2176) {
      const int c = u / 68, rem = u - c * 68;
      int r, cc;
      if (rem < 18)      { r = 0;        cc = rem + 1; }
      else if (rem < 36) { r = 17;       cc = rem - 17; }
      else if (rem < 52) { r = rem - 35; cc = 1; }
      else               { r = rem - 51; cc = 18; }
      const int gh = h0 + r, gw = wi * 16 + cc - 2;
      float v = 0.f;
      if ((unsigned)gh < 256u && (unsigned)gw < 256u)
        v = x[xb + ((size_t)c << 16) + gh * 256 + gw];
      xs[c * 360 + r * 20 + cc] = (f16)v;
    }
  }
  __syncthreads();

  const int t = tid;
  const int dh = dh_of(t), dw = dw_of(t);
  f16x8 qv[4], kv[4], vv[4];
#pragma unroll
  for (int c = 0; c < 32; ++c) {
    const f16x8 wq0 = *(const f16x8*)&wqh[c * 16];
    const f16x8 wq1 = *(const f16x8*)&wqh[c * 16 + 8];
    const f16x8 wk0 = *(const f16x8*)&wkh[c * 16];
    const f16x8 wk1 = *(const f16x8*)&wkh[c * 16 + 8];
    const int cb = c * 360 + dh * 20 + dw + 1;
    float q = bqs[c], k = bks[c];
    f16 vc = (f16)0.f;
#pragma unroll
    for (int dy = 0; dy < 3; ++dy)
#pragma unroll
      for (int dx = 0; dx < 3; ++dx) {
        const int tap = dy * 3 + dx;
        const f16 xh = xs[cb + dy * 20 + dx];
        const f16 we_q = tap < 8 ? wq0[tap & 7] : wq1[0];
        const f16 we_k = tap < 8 ? wk0[tap & 7] : wk1[0];
        q += (float)xh * (float)we_q;
        k += (float)xh * (float)we_k;
        if (dy == 1 && dx == 1) vc = xh;
      }
    qv[c >> 3][c & 7] = (f16)q;
    kv[c >> 3][c & 7] = (f16)k;
    vv[c >> 3][c & 7] = vc;
  }
  const size_t off = ((size_t)(b * NI + i)) * C4 + (size_t)t * 32;
  f16x8* Qp = (f16x8*)(Qt + off);
  f16x8* Kp = (f16x8*)(Kt + off);
  f16x8* Vp = (f16x8*)(Vt + off);
#pragma unroll
  for (int s = 0; s < 4; ++s) { Qp[s] = qv[s]; Kp[s] = kv[s]; Vp[s] = vv[s]; }
}

// ---------------------------------------------------------------------------
// K2: logits partials. S[b,i,j] = sum_c4 Qt[b,i,c4]*Kt[b,j,c4], split-K by 4.
// ---------------------------------------------------------------------------
__global__ __launch_bounds__(256) void k2_logits(
    const f16* __restrict__ Qt, const f16* __restrict__ Kt, float* __restrict__ Spart)
{
  const int b = blockIdx.z;
  const int kt = blockIdx.y;
  const int it = blockIdx.x >> 2, jt = blockIdx.x & 3;
  const int tid = threadIdx.x, wave = tid >> 6, lane = tid & 63;
  const int li = lane & 15, lk = lane >> 4;
  const int i0 = it * 64 + wave * 16;
  const int j0 = jt * 64;
  const f16* Qb = Qt + (size_t)b * NI * C4;
  const f16* Kb = Kt + (size_t)b * NI * C4;

  f32x4 acc[4] = {};
  const int kbeg = kt * 2048, kend = kbeg + 2048;
  for (int k = kbeg; k < kend; k += 32) {
    const f16x8 a = *(const f16x8*)(Qb + (size_t)(i0 + li) * C4 + k + lk * 8);
#pragma unroll
    for (int jj = 0; jj < 4; ++jj) {
      const f16x8 bb = *(const f16x8*)(Kb + (size_t)(j0 + jj * 16 + li) * C4 + k + lk * 8);
      acc[jj] = __builtin_amdgcn_mfma_f32_16x16x32_f16(a, bb, acc[jj], 0, 0, 0);
    }
  }
  float* Sp = Spart + ((size_t)kt * B_ + b) * NI * NI;
#pragma unroll
  for (int jj = 0; jj < 4; ++jj)
#pragma unroll
    for (int r = 0; r < 4; ++r) {
      const int ii = i0 + lk * 4 + r;
      const int jc = j0 + jj * 16 + li;
      Sp[(size_t)ii * NI + jc] = acc[jj][r];
    }
}

// ---------------------------------------------------------------------------
// K3: sum 4 partials + softmax over j (256), write f16. One wave per row.
// ---------------------------------------------------------------------------
__global__ __launch_bounds__(256) void k3_softmax(
    const float* __restrict__ Spart, f16* __restrict__ Sh)
{
  const int row = blockIdx.x * 4 + (threadIdx.x >> 6);  // 2048 rows
  const int lane = threadIdx.x & 63;
  const size_t base = (size_t)row * NI + lane * 4;
  f32x4 v = {0.f, 0.f, 0.f, 0.f};
#pragma unroll
  for (int kt = 0; kt < 4; ++kt) {
    const f32x4 p = *(const f32x4*)(Spart + (size_t)kt * B_ * NI * NI + base);
    v[0] += p[0]; v[1] += p[1]; v[2] += p[2]; v[3] += p[3];
  }
  float m = fmaxf(fmaxf(v[0], v[1]), fmaxf(v[2], v[3]));
#pragma unroll
  for (int d = 1; d < 64; d <<= 1) m = fmaxf(m, __shfl_xor(m, d, 64));
  const float e0 = expf(v[0] - m), e1 = expf(v[1] - m), e2 = expf(v[2] - m), e3 = expf(v[3] - m);
  float s = e0 + e1 + e2 + e3;
#pragma unroll
  for (int d = 1; d < 64; d <<= 1) s += __shfl_xor(s, d, 64);
  const float inv = 1.f / s;
  f16x4 o;
  o[0] = (f16)(e0 * inv); o[1] = (f16)(e1 * inv); o[2] = (f16)(e2 * inv); o[3] = (f16)(e3 * inv);
  *(f16x4*)(Sh + (size_t)row * NI + lane * 4) = o;
}

// ---------------------------------------------------------------------------
// K4 (fused w/ K5): E[c4,i] = sum_j V[c4,j]*S[i,j]; Y = E + V; out = w1 @ Y,
// scattered fp32 store. block = (b, t); Vs/Ys share one LDS buffer (union).
// ---------------------------------------------------------------------------
__global__ __launch_bounds__(256) void k4_ev_w1(
    const f16* __restrict__ Vt, const f16* __restrict__ Sh,
    const float* __restrict__ w1, float* __restrict__ out)
{
  __shared__ __align__(16) char smem[20480];   // max(Vs 16896, Ys 20480)
  f16* Vs = (f16*)smem;                        // [32][264] padded
  f16* Ys = (f16*)smem;                        // [256][40] padded
  __shared__ __align__(16) f16 w1s[32 * 32];
  const int bid = blockIdx.x;
  const int b = bid >> 8, t = bid & 255;
  const int tid = threadIdx.x;

#pragma unroll
  for (int e = 0; e < 4; ++e) w1s[tid + 256 * e] = (f16)w1[tid + 256 * e];

  {  // transpose-stage V panel: thread tid = column i
    const f16x8* src = (const f16x8*)(Vt + ((size_t)(b * NI + tid)) * C4 + (size_t)t * 32);
    const f16x8 v0 = src[0], v1 = src[1], v2 = src[2], v3 = src[3];
#pragma unroll
    for (int e = 0; e < 8; ++e) {
      Vs[(0 + e) * 264 + tid] = v0[e];
      Vs[(8 + e) * 264 + tid] = v1[e];
      Vs[(16 + e) * 264 + tid] = v2[e];
      Vs[(24 + e) * 264 + tid] = v3[e];
    }
  }
  __syncthreads();

  const int wave = tid >> 6, lane = tid & 63, li = lane & 15, lk = lane >> 4;
  const int i0 = wave * 64;
  const f16* Shb = Sh + (size_t)b * NI * NI;

  f32x4 acc[2][4] = {};
#pragma unroll
  for (int ks = 0; ks < 8; ++ks) {
    const int k = ks * 32 + lk * 8;
    const f16x8 a0 = *(const f16x8*)(&Vs[li * 264 + k]);
    const f16x8 a1 = *(const f16x8*)(&Vs[(16 + li) * 264 + k]);
#pragma unroll
    for (int ct = 0; ct < 4; ++ct) {
      const f16x8 bb = *(const f16x8*)(Shb + (size_t)(i0 + ct * 16 + li) * NI + k);
      acc[0][ct] = __builtin_amdgcn_mfma_f32_16x16x32_f16(a0, bb, acc[0][ct], 0, 0, 0);
      acc[1][ct] = __builtin_amdgcn_mfma_f32_16x16x32_f16(a1, bb, acc[1][ct], 0, 0, 0);
    }
  }
  // residual: Y = E + V (read Vs before overwrite)
#pragma unroll
  for (int mt = 0; mt < 2; ++mt)
#pragma unroll
    for (int ct = 0; ct < 4; ++ct)
#pragma unroll
      for (int r = 0; r < 4; ++r) {
        const int ci = mt * 16 + lk * 4 + r;
        const int ii = i0 + ct * 16 + li;
        acc[mt][ct][r] += (float)Vs[ci * 264 + ii];
      }
  __syncthreads();
  // write Y tile to LDS as [i][ci] (stride 40), packed f16x2
#pragma unroll
  for (int mt = 0; mt < 2; ++mt)
#pragma unroll
    for (int ct = 0; ct < 4; ++ct) {
      const int ii = i0 + ct * 16 + li;
#pragma unroll
      for (int rp = 0; rp < 2; ++rp) {
        const int ci0 = mt * 16 + lk * 4 + 2 * rp;
        f16x2 pv;
        pv[0] = (f16)acc[mt][ct][2 * rp];
        pv[1] = (f16)acc[mt][ct][2 * rp + 1];
        *(f16x2*)&Ys[ii * 40 + ci0] = pv;
      }
    }
  __syncthreads();

  // out[o][i] = sum_ci w1[o][ci] * Y[i][ci]; one K=32 MFMA per (o-tile, i-tile)
  const int dh = dh_of(t), dw = dw_of(t);
  const f16x8 a0 = *(const f16x8*)&w1s[li * 32 + lk * 8];         // o = li
  const f16x8 a1 = *(const f16x8*)&w1s[(16 + li) * 32 + lk * 8];  // o = 16+li
  const size_t ob = ((size_t)b * 32) << 16;
#pragma unroll
  for (int ct = 0; ct < 4; ++ct) {
    const int ii = i0 + ct * 16 + li;
    const f16x8 bfr = *(const f16x8*)&Ys[ii * 40 + lk * 8];
    f32x4 d0 = {}, d1 = {};
    d0 = __builtin_amdgcn_mfma_f32_16x16x32_f16(a0, bfr, d0, 0, 0, 0);
    d1 = __builtin_amdgcn_mfma_f32_16x16x32_f16(a1, bfr, d1, 0, 0, 0);
    const int hi_ = wave * 4 + ct;  // = ii >> 4
    const size_t rowbase = ob + (size_t)((hi_ * 16 + dh) * 256 + dw) + (size_t)li * 16;
#pragma unroll
    for (int r = 0; r < 4; ++r) {
      const int o0 = lk * 4 + r;
      out[rowbase + (((size_t)o0) << 16)] = d0[r];
      out[rowbase + (((size_t)(16 + o0)) << 16)] = d1[r];
    }
  }
}

// ---------------------------------------------------------------------------
extern "C" void kernel_launch(void* const* d_in, const int* in_sizes, int n_in,
                              void* d_out, int out_size, void* d_ws, size_t ws_size,
                              hipStream_t stream)
{
  const float* x  = (const float*)d_in[0];
  const float* wq = (const float*)d_in[1];
  const float* bq = (const float*)d_in[2];
  const float* wk = (const float*)d_in[3];
  const float* bk = (const float*)d_in[4];
  const float* w1 = (const float*)d_in[5];
  float* out = (float*)d_out;
  char* ws = (char*)d_ws;

  f16*   Qt    = (f16*)(ws);
  f16*   Kt    = (f16*)(ws + 33554432);
  f16*   Vt    = (f16*)(ws + 67108864);
  float* Spart = (float*)(ws + 100663296);
  f16*   Sh    = (f16*)(ws + 109051904);

  k1_conv_permute<<<2048, 256, 0, stream>>>(x, wq, bq, wk, bk, Qt, Kt, Vt);
  k2_logits<<<dim3(16, 4, 8), 256, 0, stream>>>(Qt, Kt, Spart);
  k3_softmax<<<512, 256, 0, stream>>>(Spart, Sh);
  k4_ev_w1<<<2048, 256, 0, stream>>>(Vt, Sh, w1, out);
}

// Round 4
// 280.519 us; speedup vs baseline: 1.1584x; 1.1584x over previous
//
#include <hip/hip_runtime.h>

#define B_ 8
#define C_ 32
#define NI 256   // coarse positions (16x16)
#define C4 8192  // merged channels = 32*256

typedef _Float16 f16;
typedef __attribute__((ext_vector_type(8))) _Float16 f16x8;
typedef __attribute__((ext_vector_type(4))) _Float16 f16x4;
typedef __attribute__((ext_vector_type(2))) _Float16 f16x2;
typedef __attribute__((ext_vector_type(4))) float f32x4;

__device__ __forceinline__ int dh_of(int t) { return (t & 1) | ((t >> 1) & 2) | ((t >> 2) & 4) | ((t >> 3) & 8); }
__device__ __forceinline__ int dw_of(int t) { return ((t >> 1) & 1) | ((t >> 2) & 2) | ((t >> 3) & 4) | ((t >> 4) & 8); }

// ---------------------------------------------------------------------------
// K1: depthwise 3x3 conv (Q,K) + identity (V), permuted to [b][i][c4] f16.
// Channel-split: block = (b, i, cg) with 16 channels -> LDS 12.7KB,
// __launch_bounds__(256,8) -> 8 blocks/CU (32 waves) for latency hiding.
// ---------------------------------------------------------------------------
__global__ __launch_bounds__(256, 8) void k1_conv_permute(
    const float* __restrict__ x, const float* __restrict__ wq, const float* __restrict__ bq,
    const float* __restrict__ wk, const float* __restrict__ bk,
    f16* __restrict__ Qt, f16* __restrict__ Kt, f16* __restrict__ Vt)
{
  __shared__ __align__(16) f16 xs[16 * 360];   // 11520 B
  __shared__ __align__(16) f16 wqh[16 * 16];   // 512 B
  __shared__ __align__(16) f16 wkh[16 * 16];   // 512 B
  __shared__ float bqs[16], bks[16];
  const int bid = blockIdx.x;
  const int cg = bid & 1;                 // channel group: 16 channels
  const int i = (bid >> 1) & 255;
  const int b = bid >> 9;
  const int hi = i >> 4, wi = i & 15;
  const int tid = threadIdx.x;

  if (tid < 144) {  // 16 ch x 9 taps
    const int c = tid / 9, t9 = tid - c * 9;
    wqh[c * 16 + t9] = (f16)wq[(cg * 16 + c) * 9 + t9];
    wkh[c * 16 + t9] = (f16)wk[(cg * 16 + c) * 9 + t9];
  }
  if (tid >= 240) { bqs[tid - 240] = bq[cg * 16 + tid - 240]; bks[tid - 240] = bk[cg * 16 + tid - 240]; }

  const size_t xb = ((size_t)(b * C_ + cg * 16)) << 16;
  // interior: 16c x 16r x 4 float4 = 1024 -> 4 per thread, aligned & coalesced
#pragma unroll
  for (int e = 0; e < 4; ++e) {
    const int u = tid + 256 * e;
    const int c = u >> 6, rem = u & 63;
    const int r16 = rem >> 2, k4 = rem & 3;
    const int gh = hi * 16 + r16, gw = wi * 16 + k4 * 4;
    const f32x4 xv = *(const f32x4*)(x + xb + ((size_t)c << 16) + gh * 256 + gw);
    const int base = c * 360 + (r16 + 1) * 20 + (2 + 4 * k4);
    f16x2 p0; p0[0] = (f16)xv[0]; p0[1] = (f16)xv[1];
    f16x2 p1; p1[0] = (f16)xv[2]; p1[1] = (f16)xv[3];
    *(f16x2*)&xs[base] = p0;
    *(f16x2*)&xs[base + 2] = p1;
  }
  // halo: 68 per channel x 16 = 1088 scalar
  const int h0 = hi * 16 - 1;
#pragma unroll
  for (int e = 0; e < 5; ++e) {
    const int u = tid + 256 * e;
    if (u < 1088) {
      const int c = u / 68, rem = u - c * 68;
      int r, cc;
      if (rem < 18)      { r = 0;        cc = rem + 1; }
      else if (rem < 36) { r = 17;       cc = rem - 17; }
      else if (rem < 52) { r = rem - 35; cc = 1; }
      else               { r = rem - 51; cc = 18; }
      const int gh = h0 + r, gw = wi * 16 + cc - 2;
      float v = 0.f;
      if ((unsigned)gh < 256u && (unsigned)gw < 256u)
        v = x[xb + ((size_t)c << 16) + gh * 256 + gw];
      xs[c * 360 + r * 20 + cc] = (f16)v;
    }
  }
  __syncthreads();

  const int t = tid;
  const int dh = dh_of(t), dw = dw_of(t);
  f16x8 qv[2], kv[2], vv[2];
#pragma unroll
  for (int c = 0; c < 16; ++c) {
    const f16x8 wq0 = *(const f16x8*)&wqh[c * 16];
    const f16x8 wq1 = *(const f16x8*)&wqh[c * 16 + 8];
    const f16x8 wk0 = *(const f16x8*)&wkh[c * 16];
    const f16x8 wk1 = *(const f16x8*)&wkh[c * 16 + 8];
    const int cb = c * 360 + dh * 20 + dw + 1;
    float q = bqs[c], k = bks[c];
    f16 vc = (f16)0.f;
#pragma unroll
    for (int dy = 0; dy < 3; ++dy)
#pragma unroll
      for (int dx = 0; dx < 3; ++dx) {
        const int tap = dy * 3 + dx;
        const f16 xh = xs[cb + dy * 20 + dx];
        const f16 we_q = tap < 8 ? wq0[tap & 7] : wq1[0];
        const f16 we_k = tap < 8 ? wk0[tap & 7] : wk1[0];
        q += (float)xh * (float)we_q;
        k += (float)xh * (float)we_k;
        if (dy == 1 && dx == 1) vc = xh;
      }
    qv[c >> 3][c & 7] = (f16)q;
    kv[c >> 3][c & 7] = (f16)k;
    vv[c >> 3][c & 7] = vc;
  }
  const size_t off = ((size_t)(b * NI + i)) * C4 + (size_t)t * 32 + cg * 16;
  f16x8* Qp = (f16x8*)(Qt + off);
  f16x8* Kp = (f16x8*)(Kt + off);
  f16x8* Vp = (f16x8*)(Vt + off);
  Qp[0] = qv[0]; Qp[1] = qv[1];
  Kp[0] = kv[0]; Kp[1] = kv[1];
  Vp[0] = vv[0]; Vp[1] = vv[1];
}

// ---------------------------------------------------------------------------
// K2: logits partials. S[b,i,j] = sum_c4 Qt[b,i,c4]*Kt[b,j,c4], split-K by 4.
// ---------------------------------------------------------------------------
__global__ __launch_bounds__(256) void k2_logits(
    const f16* __restrict__ Qt, const f16* __restrict__ Kt, float* __restrict__ Spart)
{
  const int b = blockIdx.z;
  const int kt = blockIdx.y;
  const int it = blockIdx.x >> 2, jt = blockIdx.x & 3;
  const int tid = threadIdx.x, wave = tid >> 6, lane = tid & 63;
  const int li = lane & 15, lk = lane >> 4;
  const int i0 = it * 64 + wave * 16;
  const int j0 = jt * 64;
  const f16* Qb = Qt + (size_t)b * NI * C4;
  const f16* Kb = Kt + (size_t)b * NI * C4;

  f32x4 acc[4] = {};
  const int kbeg = kt * 2048, kend = kbeg + 2048;
  for (int k = kbeg; k < kend; k += 32) {
    const f16x8 a = *(const f16x8*)(Qb + (size_t)(i0 + li) * C4 + k + lk * 8);
#pragma unroll
    for (int jj = 0; jj < 4; ++jj) {
      const f16x8 bb = *(const f16x8*)(Kb + (size_t)(j0 + jj * 16 + li) * C4 + k + lk * 8);
      acc[jj] = __builtin_amdgcn_mfma_f32_16x16x32_f16(a, bb, acc[jj], 0, 0, 0);
    }
  }
  float* Sp = Spart + ((size_t)kt * B_ + b) * NI * NI;
#pragma unroll
  for (int jj = 0; jj < 4; ++jj)
#pragma unroll
    for (int r = 0; r < 4; ++r) {
      const int ii = i0 + lk * 4 + r;
      const int jc = j0 + jj * 16 + li;
      Sp[(size_t)ii * NI + jc] = acc[jj][r];
    }
}

// ---------------------------------------------------------------------------
// K3: sum 4 partials + softmax over j (256), write f16. One wave per row.
// ---------------------------------------------------------------------------
__global__ __launch_bounds__(256) void k3_softmax(
    const float* __restrict__ Spart, f16* __restrict__ Sh)
{
  const int row = blockIdx.x * 4 + (threadIdx.x >> 6);  // 2048 rows
  const int lane = threadIdx.x & 63;
  const size_t base = (size_t)row * NI + lane * 4;
  f32x4 v = {0.f, 0.f, 0.f, 0.f};
#pragma unroll
  for (int kt = 0; kt < 4; ++kt) {
    const f32x4 p = *(const f32x4*)(Spart + (size_t)kt * B_ * NI * NI + base);
    v[0] += p[0]; v[1] += p[1]; v[2] += p[2]; v[3] += p[3];
  }
  float m = fmaxf(fmaxf(v[0], v[1]), fmaxf(v[2], v[3]));
#pragma unroll
  for (int d = 1; d < 64; d <<= 1) m = fmaxf(m, __shfl_xor(m, d, 64));
  const float e0 = expf(v[0] - m), e1 = expf(v[1] - m), e2 = expf(v[2] - m), e3 = expf(v[3] - m);
  float s = e0 + e1 + e2 + e3;
#pragma unroll
  for (int d = 1; d < 64; d <<= 1) s += __shfl_xor(s, d, 64);
  const float inv = 1.f / s;
  f16x4 o;
  o[0] = (f16)(e0 * inv); o[1] = (f16)(e1 * inv); o[2] = (f16)(e2 * inv); o[3] = (f16)(e3 * inv);
  *(f16x4*)(Sh + (size_t)row * NI + lane * 4) = o;
}

// ---------------------------------------------------------------------------
// K4: E[c4,i] = sum_j V[c4,j]*S[i,j]; Y = E + V, f16 [b][i][c4].
// block = (b, t). Y written via LDS repack -> 64B contiguous per lane.
// ---------------------------------------------------------------------------
__global__ __launch_bounds__(256) void k4_ev(
    const f16* __restrict__ Vt, const f16* __restrict__ Sh, f16* __restrict__ Y)
{
  __shared__ __align__(16) char smem[20480];   // max(Vs 16896, Ys 20480)
  f16* Vs = (f16*)smem;                        // [32][264] padded
  f16* Ys = (f16*)smem;                        // [256][40] padded
  const int bid = blockIdx.x;
  const int b = bid >> 8, t = bid & 255;
  const int tid = threadIdx.x;

  {  // transpose-stage V panel: thread tid = column i
    const f16x8* src = (const f16x8*)(Vt + ((size_t)(b * NI + tid)) * C4 + (size_t)t * 32);
    const f16x8 v0 = src[0], v1 = src[1], v2 = src[2], v3 = src[3];
#pragma unroll
    for (int e = 0; e < 8; ++e) {
      Vs[(0 + e) * 264 + tid] = v0[e];
      Vs[(8 + e) * 264 + tid] = v1[e];
      Vs[(16 + e) * 264 + tid] = v2[e];
      Vs[(24 + e) * 264 + tid] = v3[e];
    }
  }
  __syncthreads();

  const int wave = tid >> 6, lane = tid & 63, li = lane & 15, lk = lane >> 4;
  const int i0 = wave * 64;
  const f16* Shb = Sh + (size_t)b * NI * NI;

  f32x4 acc[2][4] = {};
#pragma unroll
  for (int ks = 0; ks < 8; ++ks) {
    const int k = ks * 32 + lk * 8;
    const f16x8 a0 = *(const f16x8*)(&Vs[li * 264 + k]);
    const f16x8 a1 = *(const f16x8*)(&Vs[(16 + li) * 264 + k]);
#pragma unroll
    for (int ct = 0; ct < 4; ++ct) {
      const f16x8 bb = *(const f16x8*)(Shb + (size_t)(i0 + ct * 16 + li) * NI + k);
      acc[0][ct] = __builtin_amdgcn_mfma_f32_16x16x32_f16(a0, bb, acc[0][ct], 0, 0, 0);
      acc[1][ct] = __builtin_amdgcn_mfma_f32_16x16x32_f16(a1, bb, acc[1][ct], 0, 0, 0);
    }
  }
  // residual: Y = E + V (read Vs before overwrite)
#pragma unroll
  for (int mt = 0; mt < 2; ++mt)
#pragma unroll
    for (int ct = 0; ct < 4; ++ct)
#pragma unroll
      for (int r = 0; r < 4; ++r) {
        const int ci = mt * 16 + lk * 4 + r;
        const int ii = i0 + ct * 16 + li;
        acc[mt][ct][r] += (float)Vs[ci * 264 + ii];
      }
  __syncthreads();
  // repack Y tile to LDS as [i][ci] (stride 40), packed f16x2
#pragma unroll
  for (int mt = 0; mt < 2; ++mt)
#pragma unroll
    for (int ct = 0; ct < 4; ++ct) {
      const int ii = i0 + ct * 16 + li;
#pragma unroll
      for (int rp = 0; rp < 2; ++rp) {
        const int ci0 = mt * 16 + lk * 4 + 2 * rp;
        f16x2 pv;
        pv[0] = (f16)acc[mt][ct][2 * rp];
        pv[1] = (f16)acc[mt][ct][2 * rp + 1];
        *(f16x2*)&Ys[ii * 40 + ci0] = pv;
      }
    }
  __syncthreads();
  // store: thread tid = row i, 64B contiguous
  {
    f16x8* dst = (f16x8*)(Y + ((size_t)(b * NI + tid)) * C4 + (size_t)t * 32);
    dst[0] = *(const f16x8*)&Ys[tid * 40 + 0];
    dst[1] = *(const f16x8*)&Ys[tid * 40 + 8];
    dst[2] = *(const f16x8*)&Ys[tid * 40 + 16];
    dst[3] = *(const f16x8*)&Ys[tid * 40 + 24];
  }
}

// ---------------------------------------------------------------------------
// K5: out[b,o,h,w] = sum_ci w1[o,ci] * Y[b, i(h,w), t(h,w)*32+ci], fp32 out.
// block = (b, i): all 256 t -> every touched 64B out-line is fully written
// by this block (L2 merges) -> clean 64MB HBM write.
// ---------------------------------------------------------------------------
__global__ __launch_bounds__(256) void k5_w1_unpermute(
    const f16* __restrict__ Y, const float* __restrict__ w1, float* __restrict__ out)
{
  __shared__ f16 w1s[32 * 32];
  const int bid = blockIdx.x;
  const int b = bid >> 8, i = bid & 255;
  const int hi = i >> 4, wi = i & 15;
  const int tid = threadIdx.x;
#pragma unroll
  for (int e = 0; e < 4; ++e) w1s[tid + 256 * e] = (f16)w1[tid + 256 * e];
  __syncthreads();

  const int wave = tid >> 6, lane = tid & 63, li = lane & 15, lk = lane >> 4;
  const f16* Yrow = Y + ((size_t)(b * NI + i)) * C4;
  const f16x8 b0 = *(const f16x8*)(&w1s[li * 32 + lk * 8]);         // o = li
  const f16x8 b1 = *(const f16x8*)(&w1s[(16 + li) * 32 + lk * 8]);  // o = 16+li

#pragma unroll
  for (int q = 0; q < 4; ++q) {
    const int tt = wave * 4 + q;
    const f16x8 a = *(const f16x8*)(Yrow + (size_t)(tt * 16 + li) * 32 + lk * 8);
    f32x4 d0 = {}, d1 = {};
    d0 = __builtin_amdgcn_mfma_f32_16x16x32_f16(a, b0, d0, 0, 0, 0);
    d1 = __builtin_amdgcn_mfma_f32_16x16x32_f16(a, b1, d1, 0, 0, 0);
#pragma unroll
    for (int r = 0; r < 4; ++r) {
      const int t = tt * 16 + lk * 4 + r;
      const int dh = dh_of(t), dw = dw_of(t);
      const int h = hi * 16 + dh, w = wi * 16 + dw;
      out[(((size_t)(b * 32 + li)) * 256 + h) * 256 + w] = d0[r];
      out[(((size_t)(b * 32 + 16 + li)) * 256 + h) * 256 + w] = d1[r];
    }
  }
}

// ---------------------------------------------------------------------------
extern "C" void kernel_launch(void* const* d_in, const int* in_sizes, int n_in,
                              void* d_out, int out_size, void* d_ws, size_t ws_size,
                              hipStream_t stream)
{
  const float* x  = (const float*)d_in[0];
  const float* wq = (const float*)d_in[1];
  const float* bq = (const float*)d_in[2];
  const float* wk = (const float*)d_in[3];
  const float* bk = (const float*)d_in[4];
  const float* w1 = (const float*)d_in[5];
  float* out = (float*)d_out;
  char* ws = (char*)d_ws;

  f16*   Qt    = (f16*)(ws);
  f16*   Kt    = (f16*)(ws + 33554432);
  f16*   Vt    = (f16*)(ws + 67108864);
  float* Spart = (float*)(ws + 100663296);
  f16*   Sh    = (f16*)(ws + 109051904);
  f16*   Y     = Qt;  // Qt dead after K2

  k1_conv_permute<<<4096, 256, 0, stream>>>(x, wq, bq, wk, bk, Qt, Kt, Vt);
  k2_logits<<<dim3(16, 4, 8), 256, 0, stream>>>(Qt, Kt, Spart);
  k3_softmax<<<512, 256, 0, stream>>>(Spart, Sh);
  k4_ev<<<2048, 256, 0, stream>>>(Vt, Sh, Y);
  k5_w1_unpermute<<<2048, 256, 0, stream>>>(Y, w1, out);
}

// Round 5
// 182.183 us; speedup vs baseline: 1.7836x; 1.5398x over previous
//
#include <hip/hip_runtime.h>

#define B_ 8
#define C_ 32
#define NI 256   // coarse positions (16x16)
#define C4 8192  // merged channels = 32*256

typedef _Float16 f16;
typedef __attribute__((ext_vector_type(8))) _Float16 f16x8;
typedef __attribute__((ext_vector_type(4))) _Float16 f16x4;
typedef __attribute__((ext_vector_type(2))) _Float16 f16x2;
typedef __attribute__((ext_vector_type(4))) float f32x4;

__device__ __forceinline__ int dh_of(int t) { return (t & 1) | ((t >> 1) & 2) | ((t >> 2) & 4) | ((t >> 3) & 8); }
__device__ __forceinline__ int dw_of(int t) { return ((t >> 1) & 1) | ((t >> 2) & 2) | ((t >> 3) & 4) | ((t >> 4) & 8); }
// t from pixel-in-tile (hl, w): bits t0=hl0,t1=w0,t2=hl1,t3=w1,t4=hl2,t5=w2,t6=hl3,t7=w3
__device__ __forceinline__ int t_of(int hl, int w) {
  return (hl & 1) | ((w & 1) << 1) | ((hl & 2) << 1) | ((w & 2) << 2)
       | ((hl & 4) << 2) | ((w & 4) << 3) | ((hl & 8) << 3) | ((w & 8) << 4);
}

// ---------------------------------------------------------------------------
// K1a: depthwise 3x3 conv in NATURAL layout. Q,K f16 [b][c][h][w].
// Pure streaming: no LDS, no barriers. Thread = (b,c,h,16-w-group):
// 16 outputs via register row-sliding; f32 weights; 32B vec stores.
// ---------------------------------------------------------------------------
__global__ __launch_bounds__(256) void k1a_conv(
    const float* __restrict__ x, const float* __restrict__ wq, const float* __restrict__ bq,
    const float* __restrict__ wk, const float* __restrict__ bk,
    f16* __restrict__ Qn, f16* __restrict__ Kn)
{
  const int u = blockIdx.x * 256 + threadIdx.x;
  const int wg = u & 15, h = (u >> 4) & 255, c = (u >> 12) & 31, b = u >> 17;
  const int w0 = wg * 16;
  const size_t cimg = ((size_t)(b * 32 + c)) << 16;

  float wtq[9], wtk[9];
#pragma unroll
  for (int t = 0; t < 9; ++t) { wtq[t] = wq[c * 9 + t]; wtk[t] = wk[c * 9 + t]; }
  const float bqv = bq[c], bkv = bk[c];

  float q[16], k[16];
#pragma unroll
  for (int w = 0; w < 16; ++w) { q[w] = bqv; k[w] = bkv; }

#pragma unroll
  for (int dy = 0; dy < 3; ++dy) {
    const int gh = h - 1 + dy;
    if ((unsigned)gh < 256u) {
      const float* p = x + cimg + (size_t)gh * 256 + w0;
      float r[18];
      const f32x4 a0 = *(const f32x4*)(p);
      const f32x4 a1 = *(const f32x4*)(p + 4);
      const f32x4 a2 = *(const f32x4*)(p + 8);
      const f32x4 a3 = *(const f32x4*)(p + 12);
#pragma unroll
      for (int e = 0; e < 4; ++e) { r[1 + e] = a0[e]; r[5 + e] = a1[e]; r[9 + e] = a2[e]; r[13 + e] = a3[e]; }
      r[0]  = (w0 > 0)        ? p[-1] : 0.f;
      r[17] = (w0 + 16 < 256) ? p[16] : 0.f;
      const float q0 = wtq[dy * 3], q1 = wtq[dy * 3 + 1], q2 = wtq[dy * 3 + 2];
      const float k0 = wtk[dy * 3], k1 = wtk[dy * 3 + 1], k2 = wtk[dy * 3 + 2];
#pragma unroll
      for (int w = 0; w < 16; ++w) {
        q[w] += r[w] * q0 + r[w + 1] * q1 + r[w + 2] * q2;
        k[w] += r[w] * k0 + r[w + 1] * k1 + r[w + 2] * k2;
      }
    }
  }
  f16x8 qo[2], ko[2];
#pragma unroll
  for (int w = 0; w < 16; ++w) { qo[w >> 3][w & 7] = (f16)q[w]; ko[w >> 3][w & 7] = (f16)k[w]; }
  f16x8* qp = (f16x8*)(Qn + cimg + (size_t)h * 256 + w0);
  f16x8* kp = (f16x8*)(Kn + cimg + (size_t)h * 256 + w0);
  qp[0] = qo[0]; qp[1] = qo[1];
  kp[0] = ko[0]; kp[1] = ko[1];
}

// ---------------------------------------------------------------------------
// K1v: V = x (f16), permuted to [b][i][c4] via one LDS transpose.
// block = (b,i): coalesced row loads -> LDS [c][t] (pad 273) -> 64B vec stores.
// ---------------------------------------------------------------------------
__global__ __launch_bounds__(256) void k1v_permute(
    const float* __restrict__ x, f16* __restrict__ Vt)
{
  __shared__ f16 vls[32 * 273];   // 17472 B, odd stride spreads banks
  const int bid = blockIdx.x;
  const int b = bid >> 8, i = bid & 255;
  const int hi = i >> 4, wi = i & 15;
  const int tid = threadIdx.x;

#pragma unroll
  for (int tt = 0; tt < 2; ++tt) {
    const int c = (tid >> 4) + tt * 16, hl = tid & 15;
    const float* p = x + (((size_t)(b * 32 + c)) << 16) + (size_t)(hi * 16 + hl) * 256 + wi * 16;
    const f32x4 a0 = *(const f32x4*)(p);
    const f32x4 a1 = *(const f32x4*)(p + 4);
    const f32x4 a2 = *(const f32x4*)(p + 8);
    const f32x4 a3 = *(const f32x4*)(p + 12);
    float r[16];
#pragma unroll
    for (int e = 0; e < 4; ++e) { r[e] = a0[e]; r[4 + e] = a1[e]; r[8 + e] = a2[e]; r[12 + e] = a3[e]; }
#pragma unroll
    for (int w = 0; w < 16; ++w) vls[c * 273 + t_of(hl, w)] = (f16)r[w];
  }
  __syncthreads();

  f16x8 o[4];
#pragma unroll
  for (int c = 0; c < 32; ++c) o[c >> 3][c & 7] = vls[c * 273 + tid];
  f16x8* dst = (f16x8*)(Vt + ((size_t)(b * NI + i)) * C4 + (size_t)tid * 32);
  dst[0] = o[0]; dst[1] = o[1]; dst[2] = o[2]; dst[3] = o[3];
}

// ---------------------------------------------------------------------------
// K2: logits partials from NATURAL-layout Qn/Kn. k enumerated as (c, dh, dw):
// Q[i,k] = Qn[b][c][(i>>4)*16+dh][(i&15)*16+dw]. Frag loads stay 16B
// contiguous, wave-coalesced (lane li <-> wi). Split-K by 4.
// ---------------------------------------------------------------------------
__global__ __launch_bounds__(256) void k2_logits(
    const f16* __restrict__ Qn, const f16* __restrict__ Kn, float* __restrict__ Spart)
{
  const int b = blockIdx.z;
  const int kt = blockIdx.y;
  const int it = blockIdx.x >> 2, jt = blockIdx.x & 3;
  const int tid = threadIdx.x, wave = tid >> 6, lane = tid & 63;
  const int li = lane & 15, lk = lane >> 4;
  const int i0 = it * 64 + wave * 16;   // multiple of 16 -> pixel-row base = i0
  const int j0 = jt * 64;
  const f16* Qb = Qn + ((size_t)b << 21);
  const f16* Kb = Kn + ((size_t)b << 21);
  const int dhl = lk >> 1, dwl = (lk & 1) * 8;

  f32x4 acc[4] = {};
  const int kbeg = kt * 2048, kend = kbeg + 2048;
  for (int kk = kbeg; kk < kend; kk += 32) {
    const int c = kk >> 8, dhb = (kk >> 4) & 15;
    const size_t cbase = ((size_t)c << 16) + (size_t)(dhb + dhl) * 256 + li * 16 + dwl;
    const f16x8 a = *(const f16x8*)(Qb + cbase + (size_t)i0 * 256);
#pragma unroll
    for (int jj = 0; jj < 4; ++jj) {
      const f16x8 bb = *(const f16x8*)(Kb + cbase + (size_t)(j0 + jj * 16) * 256);
      acc[jj] = __builtin_amdgcn_mfma_f32_16x16x32_f16(a, bb, acc[jj], 0, 0, 0);
    }
  }
  float* Sp = Spart + ((size_t)kt * B_ + b) * NI * NI;
#pragma unroll
  for (int jj = 0; jj < 4; ++jj)
#pragma unroll
    for (int r = 0; r < 4; ++r) {
      const int ii = i0 + lk * 4 + r;
      const int jc = j0 + jj * 16 + li;
      Sp[(size_t)ii * NI + jc] = acc[jj][r];
    }
}

// ---------------------------------------------------------------------------
// K3: sum 4 partials + softmax over j (256), write f16. One wave per row.
// ---------------------------------------------------------------------------
__global__ __launch_bounds__(256) void k3_softmax(
    const float* __restrict__ Spart, f16* __restrict__ Sh)
{
  const int row = blockIdx.x * 4 + (threadIdx.x >> 6);  // 2048 rows
  const int lane = threadIdx.x & 63;
  const size_t base = (size_t)row * NI + lane * 4;
  f32x4 v = {0.f, 0.f, 0.f, 0.f};
#pragma unroll
  for (int kt = 0; kt < 4; ++kt) {
    const f32x4 p = *(const f32x4*)(Spart + (size_t)kt * B_ * NI * NI + base);
    v[0] += p[0]; v[1] += p[1]; v[2] += p[2]; v[3] += p[3];
  }
  float m = fmaxf(fmaxf(v[0], v[1]), fmaxf(v[2], v[3]));
#pragma unroll
  for (int d = 1; d < 64; d <<= 1) m = fmaxf(m, __shfl_xor(m, d, 64));
  const float e0 = expf(v[0] - m), e1 = expf(v[1] - m), e2 = expf(v[2] - m), e3 = expf(v[3] - m);
  float s = e0 + e1 + e2 + e3;
#pragma unroll
  for (int d = 1; d < 64; d <<= 1) s += __shfl_xor(s, d, 64);
  const float inv = 1.f / s;
  f16x4 o;
  o[0] = (f16)(e0 * inv); o[1] = (f16)(e1 * inv); o[2] = (f16)(e2 * inv); o[3] = (f16)(e3 * inv);
  *(f16x4*)(Sh + (size_t)row * NI + lane * 4) = o;
}

// ---------------------------------------------------------------------------
// K4: E[c4,i] = sum_j V[c4,j]*S[i,j]; Y = E + V, f16 [b][i][c4].
// block = (b, t). Y written via LDS repack -> 64B contiguous per lane.
// ---------------------------------------------------------------------------
__global__ __launch_bounds__(256) void k4_ev(
    const f16* __restrict__ Vt, const f16* __restrict__ Sh, f16* __restrict__ Y)
{
  __shared__ __align__(16) char smem[20480];   // max(Vs 16896, Ys 20480)
  f16* Vs = (f16*)smem;                        // [32][264] padded
  f16* Ys = (f16*)smem;                        // [256][40] padded
  const int bid = blockIdx.x;
  const int b = bid >> 8, t = bid & 255;
  const int tid = threadIdx.x;

  {  // transpose-stage V panel: thread tid = column i
    const f16x8* src = (const f16x8*)(Vt + ((size_t)(b * NI + tid)) * C4 + (size_t)t * 32);
    const f16x8 v0 = src[0], v1 = src[1], v2 = src[2], v3 = src[3];
#pragma unroll
    for (int e = 0; e < 8; ++e) {
      Vs[(0 + e) * 264 + tid] = v0[e];
      Vs[(8 + e) * 264 + tid] = v1[e];
      Vs[(16 + e) * 264 + tid] = v2[e];
      Vs[(24 + e) * 264 + tid] = v3[e];
    }
  }
  __syncthreads();

  const int wave = tid >> 6, lane = tid & 63, li = lane & 15, lk = lane >> 4;
  const int i0 = wave * 64;
  const f16* Shb = Sh + (size_t)b * NI * NI;

  f32x4 acc[2][4] = {};
#pragma unroll
  for (int ks = 0; ks < 8; ++ks) {
    const int k = ks * 32 + lk * 8;
    const f16x8 a0 = *(const f16x8*)(&Vs[li * 264 + k]);
    const f16x8 a1 = *(const f16x8*)(&Vs[(16 + li) * 264 + k]);
#pragma unroll
    for (int ct = 0; ct < 4; ++ct) {
      const f16x8 bb = *(const f16x8*)(Shb + (size_t)(i0 + ct * 16 + li) * NI + k);
      acc[0][ct] = __builtin_amdgcn_mfma_f32_16x16x32_f16(a0, bb, acc[0][ct], 0, 0, 0);
      acc[1][ct] = __builtin_amdgcn_mfma_f32_16x16x32_f16(a1, bb, acc[1][ct], 0, 0, 0);
    }
  }
  // residual: Y = E + V (read Vs before overwrite)
#pragma unroll
  for (int mt = 0; mt < 2; ++mt)
#pragma unroll
    for (int ct = 0; ct < 4; ++ct)
#pragma unroll
      for (int r = 0; r < 4; ++r) {
        const int ci = mt * 16 + lk * 4 + r;
        const int ii = i0 + ct * 16 + li;
        acc[mt][ct][r] += (float)Vs[ci * 264 + ii];
      }
  __syncthreads();
  // repack Y tile to LDS as [i][ci] (stride 40), packed f16x2
#pragma unroll
  for (int mt = 0; mt < 2; ++mt)
#pragma unroll
    for (int ct = 0; ct < 4; ++ct) {
      const int ii = i0 + ct * 16 + li;
#pragma unroll
      for (int rp = 0; rp < 2; ++rp) {
        const int ci0 = mt * 16 + lk * 4 + 2 * rp;
        f16x2 pv;
        pv[0] = (f16)acc[mt][ct][2 * rp];
        pv[1] = (f16)acc[mt][ct][2 * rp + 1];
        *(f16x2*)&Ys[ii * 40 + ci0] = pv;
      }
    }
  __syncthreads();
  // store: thread tid = row i, 64B contiguous
  {
    f16x8* dst = (f16x8*)(Y + ((size_t)(b * NI + tid)) * C4 + (size_t)t * 32);
    dst[0] = *(const f16x8*)&Ys[tid * 40 + 0];
    dst[1] = *(const f16x8*)&Ys[tid * 40 + 8];
    dst[2] = *(const f16x8*)&Ys[tid * 40 + 16];
    dst[3] = *(const f16x8*)&Ys[tid * 40 + 24];
  }
}

// ---------------------------------------------------------------------------
// K5: out[b,o,h,w] = sum_ci w1[o,ci] * Y[b, i(h,w), t(h,w)*32+ci], fp32 out.
// block = (b, i): all 256 t -> full 64B-line coverage, L2 merges stores.
// ---------------------------------------------------------------------------
__global__ __launch_bounds__(256) void k5_w1_unpermute(
    const f16* __restrict__ Y, const float* __restrict__ w1, float* __restrict__ out)
{
  __shared__ f16 w1s[32 * 32];
  const int bid = blockIdx.x;
  const int b = bid >> 8, i = bid & 255;
  const int hi = i >> 4, wi = i & 15;
  const int tid = threadIdx.x;
#pragma unroll
  for (int e = 0; e < 4; ++e) w1s[tid + 256 * e] = (f16)w1[tid + 256 * e];
  __syncthreads();

  const int wave = tid >> 6, lane = tid & 63, li = lane & 15, lk = lane >> 4;
  const f16* Yrow = Y + ((size_t)(b * NI + i)) * C4;
  const f16x8 b0 = *(const f16x8*)(&w1s[li * 32 + lk * 8]);         // o = li
  const f16x8 b1 = *(const f16x8*)(&w1s[(16 + li) * 32 + lk * 8]);  // o = 16+li

#pragma unroll
  for (int q = 0; q < 4; ++q) {
    const int tt = wave * 4 + q;
    const f16x8 a = *(const f16x8*)(Yrow + (size_t)(tt * 16 + li) * 32 + lk * 8);
    f32x4 d0 = {}, d1 = {};
    d0 = __builtin_amdgcn_mfma_f32_16x16x32_f16(a, b0, d0, 0, 0, 0);
    d1 = __builtin_amdgcn_mfma_f32_16x16x32_f16(a, b1, d1, 0, 0, 0);
#pragma unroll
    for (int r = 0; r < 4; ++r) {
      const int t = tt * 16 + lk * 4 + r;
      const int dh = dh_of(t), dw = dw_of(t);
      const int h = hi * 16 + dh, w = wi * 16 + dw;
      out[(((size_t)(b * 32 + li)) * 256 + h) * 256 + w] = d0[r];
      out[(((size_t)(b * 32 + 16 + li)) * 256 + h) * 256 + w] = d1[r];
    }
  }
}

// ---------------------------------------------------------------------------
extern "C" void kernel_launch(void* const* d_in, const int* in_sizes, int n_in,
                              void* d_out, int out_size, void* d_ws, size_t ws_size,
                              hipStream_t stream)
{
  const float* x  = (const float*)d_in[0];
  const float* wq = (const float*)d_in[1];
  const float* bq = (const float*)d_in[2];
  const float* wk = (const float*)d_in[3];
  const float* bk = (const float*)d_in[4];
  const float* w1 = (const float*)d_in[5];
  float* out = (float*)d_out;
  char* ws = (char*)d_ws;

  // ws: Qn [0,32M) natural | Kn [32M,64M) natural | Vt [64M,96M) permuted
  //     Spart [96M,104M) | Sh [104M,105M).  Y aliases Qn (dead after K2).
  f16*   Qn    = (f16*)(ws);
  f16*   Kn    = (f16*)(ws + 33554432);
  f16*   Vt    = (f16*)(ws + 67108864);
  float* Spart = (float*)(ws + 100663296);
  f16*   Sh    = (f16*)(ws + 109051904);
  f16*   Y     = Qn;

  k1a_conv<<<4096, 256, 0, stream>>>(x, wq, bq, wk, bk, Qn, Kn);
  k1v_permute<<<2048, 256, 0, stream>>>(x, Vt);
  k2_logits<<<dim3(16, 4, 8), 256, 0, stream>>>(Qn, Kn, Spart);
  k3_softmax<<<512, 256, 0, stream>>>(Spart, Sh);
  k4_ev<<<2048, 256, 0, stream>>>(Vt, Sh, Y);
  k5_w1_unpermute<<<2048, 256, 0, stream>>>(Y, w1, out);
}